// Round 7
// baseline (670.900 us; speedup 1.0000x reference)
//
#include <hip/hip_runtime.h>
#include <stdint.h>
#include <stddef.h>

#define B_ 4
#define S_ 2048
#define D_ 1024
#define H_ 16
#define DK_ 64
#define M_ (B_*S_)
#define NEGINF (-1e30f)
#define THR_ 8.0f

#if __has_builtin(__builtin_amdgcn_exp2f)
#define EXP2F(x) __builtin_amdgcn_exp2f(x)
#else
#define EXP2F(x) exp2f(x)
#endif

typedef _Float16 f16;
typedef __attribute__((ext_vector_type(8))) _Float16 f16x8;
typedef __attribute__((ext_vector_type(4))) _Float16 f16x4;
typedef __attribute__((ext_vector_type(4))) float f32x4;

// async global->LDS, 16B per lane; LDS dest = wave-uniform base + lane*16
__device__ __forceinline__ void gload16(const void* g, void* l) {
  __builtin_amdgcn_global_load_lds(
      (const __attribute__((address_space(1))) uint32_t*)g,
      (__attribute__((address_space(3))) uint32_t*)l, 16, 0, 0);
}

// ---------------- convert src f32 -> f16 ----------------
__global__ void k_cvt_src(const float* __restrict__ in, f16* __restrict__ out) {
  int i = blockIdx.x*256 + threadIdx.x;
  const f32x4* p = (const f32x4*)in;
  f32x4 a = p[2*i], b = p[2*i+1];
  f16x8 o;
  o[0]=(f16)a[0]; o[1]=(f16)a[1]; o[2]=(f16)a[2]; o[3]=(f16)a[3];
  o[4]=(f16)b[0]; o[5]=(f16)b[1]; o[6]=(f16)b[2]; o[7]=(f16)b[3];
  ((f16x8*)out)[i] = o;
}

// ---------------- convert + transpose W[k][n] -> Wt[n][k] f16 ----------------
__global__ void k_cvt_wt(const float* __restrict__ W, f16* __restrict__ Wt) {
  __shared__ float tile[64][65];
  int k0 = blockIdx.x*64, n0 = blockIdx.y*64;
  int t = threadIdx.x;
  int c4 = t & 15, r0 = t >> 4;
  #pragma unroll
  for (int i = 0; i < 4; i++) {
    int r = r0 + i*16;
    f32x4 v = *(const f32x4*)&W[(size_t)(k0 + r)*D_ + n0 + c4*4];
    tile[r][c4*4+0]=v[0]; tile[r][c4*4+1]=v[1]; tile[r][c4*4+2]=v[2]; tile[r][c4*4+3]=v[3];
  }
  __syncthreads();
  #pragma unroll
  for (int i = 0; i < 4; i++) {
    int nr = r0 + i*16;
    int kc = c4*4;
    f16x4 o;
    o[0]=(f16)tile[kc+0][nr]; o[1]=(f16)tile[kc+1][nr];
    o[2]=(f16)tile[kc+2][nr]; o[3]=(f16)tile[kc+3][nr];
    *(f16x4*)&Wt[(size_t)(n0+nr)*D_ + k0 + kc] = o;
  }
}

// ---------------- bool(int32) mask -> bitmask words ----------------
__global__ void k_mask_words(const int* __restrict__ m, uint32_t* __restrict__ words) {
  int gw = (blockIdx.x*256 + threadIdx.x) >> 6;
  int lane = threadIdx.x & 63;
  int v = m[(size_t)gw*64 + lane];
  unsigned long long bal = __ballot(v != 0);
  if (lane == 0) { words[gw*2] = (uint32_t)bal; words[gw*2+1] = (uint32_t)(bal>>32); }
}

// ---------------- GEMM (m97 structure): C[m][n] = A[m][:]*Wt[n][:] + bias ----------------
// MODE 0: Q out f16, scaled by 0.125*log2(e).  MODE 1: K out f16.
// MODE 2: V out f16 transposed -> Vt[bh][dk][s].  MODE 3: f32 out.
template<int MODE>
__global__ __launch_bounds__(256, 2) void k_gemm(
    const f16* __restrict__ A, const f16* __restrict__ Wt,
    const float* __restrict__ bias, void* __restrict__ outp) {
  __shared__ f16 As[128][64];   // linear: required by global_load_lds
  __shared__ f16 Bs[128][64];
  const int t = threadIdx.x;
  const int wave = t>>6, lane = t&63;
  const int lr = lane&15, lg = lane>>4;
  const int wr = wave>>1, wc = wave&1;
  const int m0 = blockIdx.y*128, n0 = blockIdx.x*128;
  const int srow = lane>>3, scol = (lane&7)*8;

  const f16* ga = A  + (size_t)m0*D_;
  const f16* gb = Wt + (size_t)n0*D_;

  f32x4 acc[4][4] = {};
  for (int kk=0; kk<16; kk++) {
    __syncthreads();
    #pragma unroll
    for (int i=0;i<4;i++){
      int rbase = i*32 + wave*8;
      gload16(&ga[(size_t)(rbase+srow)*D_ + kk*64 + scol], &As[rbase][0]);
      gload16(&gb[(size_t)(rbase+srow)*D_ + kk*64 + scol], &Bs[rbase][0]);
    }
    __syncthreads();   // drains vmcnt(0): tiles ready
    #pragma unroll
    for (int s=0;s<2;s++) {
      f16x8 af[4], bf[4];
      #pragma unroll
      for (int i=0;i<4;i++) af[i] = *(const f16x8*)&As[wr*64 + i*16 + lr][s*32 + lg*8];
      #pragma unroll
      for (int i=0;i<4;i++) bf[i] = *(const f16x8*)&Bs[wc*64 + i*16 + lr][s*32 + lg*8];
      #pragma unroll
      for (int i=0;i<4;i++)
        #pragma unroll
        for (int j=0;j<4;j++)
          acc[i][j] = __builtin_amdgcn_mfma_f32_16x16x32_f16(af[i], bf[j], acc[i][j],0,0,0);
    }
  }
  #pragma unroll
  for (int fn=0; fn<4; fn++) {
    int n = n0 + wc*64 + fn*16 + lr;
    float bv = bias[n];
    #pragma unroll
    for (int fm=0; fm<4; fm++) {
      int mrow = m0 + wr*64 + fm*16 + lg*4;
      if constexpr (MODE == 0) {
        f16* O = (f16*)outp;
        #pragma unroll
        for (int j=0;j<4;j++) O[(size_t)(mrow+j)*D_ + n] = (f16)((acc[fm][fn][j] + bv)*0.1803368801111204f);
      } else if constexpr (MODE == 1) {
        f16* O = (f16*)outp;
        #pragma unroll
        for (int j=0;j<4;j++) O[(size_t)(mrow+j)*D_ + n] = (f16)(acc[fm][fn][j] + bv);
      } else if constexpr (MODE == 2) {
        f16* O = (f16*)outp;
        int hh = n >> 6, dk = n & 63;
        int bb = mrow >> 11, ss = mrow & (S_-1);
        f16x4 o;
        #pragma unroll
        for (int j=0;j<4;j++) o[j] = (f16)(acc[fm][fn][j] + bv);
        *(f16x4*)&O[((size_t)(bb*H_ + hh)*DK_ + dk)*S_ + ss] = o;
      } else {
        float* O = (float*)outp;
        #pragma unroll
        for (int j=0;j<4;j++) O[(size_t)(mrow+j)*D_ + n] = acc[fm][fn][j] + bv;
      }
    }
  }
}

// ---------------- stats pass: QK^T + per-lane online max/sum; no LDS, no barriers ----------------
// kf fragments loaded directly from global (K is L2-resident: 16.8 MB < 32 MB L2).
// Lane's 4 scores = keys 4*lr+f (same mapping as the LDS key-permute, now by address).
__global__ __launch_bounds__(256, 2) void k_stats(
    const f16* __restrict__ Qh, const f16* __restrict__ Kh,
    const uint32_t* __restrict__ amw, const uint32_t* __restrict__ kpw,
    float2* __restrict__ stats) {
  const int t = threadIdx.x, wave = t>>6, lane = t&63;
  const int lr = lane&15, lg = lane>>4;
  const int sh4 = 4*lr;
  const int flat = blockIdx.x;
  const int vid = (flat & 7)*128 + (flat >> 3);   // XCD swizzle: 8 bh per XCD
  const int bh = vid >> 4, qt = vid & 15;
  const int b = bh >> 4, h = bh & 15;
  const int qb = qt*128 + wave*32;

  const f16* kbase = Kh + (size_t)b*S_*D_ + h*64;

  f16x8 qf[2][2];
  #pragma unroll
  for (int qi=0; qi<2; qi++)
    #pragma unroll
    for (int s=0; s<2; s++)
      qf[qi][s] = *(const f16x8*)&Qh[(size_t)(b*S_ + qb + qi*16 + lr)*D_ + h*64 + s*32 + lg*8];

  float mu[2][4], mg[2][4], l_[2][4];
  #pragma unroll
  for (int qi=0;qi<2;qi++)
    #pragma unroll
    for (int j=0;j<4;j++){ mu[qi][j]=NEGINF; mg[qi][j]=0.f; l_[qi][j]=0.f; }

  for (int kt=0; kt<32; kt++) {
    f32x4 sf[2][4] = {};
    #pragma unroll
    for (int s=0;s<2;s++)
      #pragma unroll
      for (int f=0;f<4;f++) {
        f16x8 kf = *(const f16x8*)&kbase[(size_t)(kt*64 + 4*lr + f)*D_ + s*32 + lg*8];
        #pragma unroll
        for (int qi=0;qi<2;qi++)
          sf[qi][f] = __builtin_amdgcn_mfma_f32_16x16x32_f16(qf[qi][s], kf, sf[qi][f],0,0,0);
      }
    uint2 kw = *(const uint2*)&kpw[b*64 + kt*2];
    #pragma unroll
    for (int qi=0;qi<2;qi++)
      #pragma unroll
      for (int j=0;j<4;j++) {
        int qrow = qb + qi*16 + lg*4 + j;
        uint2 aw = *(const uint2*)&amw[(size_t)qrow*64 + kt*2];
        uint32_t a0 = aw.x | kw.x, a1 = aw.y | kw.y;
        int nb = (int)((((uint64_t)a1<<32) | a0) >> sh4) & 15;
        float x0 = (nb&1) ? NEGINF : sf[qi][0][j];
        float x1 = (nb&2) ? NEGINF : sf[qi][1][j];
        float x2 = (nb&4) ? NEGINF : sf[qi][2][j];
        float x3 = (nb&8) ? NEGINF : sf[qi][3][j];
        float tm = fmaxf(fmaxf(x0,x1), fmaxf(x2,x3));
        if (tm > mu[qi][j] + THR_) {   // per-lane defer-max rescale (rare)
          l_[qi][j] *= EXP2F(mg[qi][j] - tm);
          mu[qi][j] = tm; mg[qi][j] = tm;
        }
        float mgv = mg[qi][j];
        l_[qi][j] += (EXP2F(x0-mgv)+EXP2F(x1-mgv))+(EXP2F(x2-mgv)+EXP2F(x3-mgv));
      }
  }

  // merge across the 16 lr-lanes of each row; publish (max, 1/l)
  #pragma unroll
  for (int qi=0;qi<2;qi++)
    #pragma unroll
    for (int j=0;j<4;j++) {
      float M = mu[qi][j];
      #pragma unroll
      for (int d=1; d<16; d<<=1) M = fmaxf(M, __shfl_xor(M, d));
      float M2 = (M <= NEGINF) ? 0.f : M;
      float lc = l_[qi][j] * EXP2F(mg[qi][j] - M2);
      #pragma unroll
      for (int d=1; d<16; d<<=1) lc += __shfl_xor(lc, d);
      if (lr == 0)
        stats[(size_t)bh*S_ + qb + qi*16 + lg*4 + j] =
            make_float2(M2, (lc > 0.f) ? 1.f/lc : 0.f);
    }
}

// ---------------- fused attn-write + PV: no barriers, K/V fragments from L2 ----------------
// Per kt: QK^T -> masked exp2 -> nontemporal attn store + normalized P->f16 (per-wave Pl
// bounce, same-wave lgkmcnt ordering only) -> PV MFMA. Context is final (P pre-normalized).
__global__ __launch_bounds__(256, 2) void k_attn2(
    const f16* __restrict__ Qh, const f16* __restrict__ Kh, const f16* __restrict__ Vt,
    const uint32_t* __restrict__ amw, const uint32_t* __restrict__ kpw,
    const float2* __restrict__ stats, float* __restrict__ attnp, f16* __restrict__ ctx) {
  __shared__ f16 Pl[4][32][72];   // per-wave P bounce only (18.4 KB total)

  const int t = threadIdx.x, wave = t>>6, lane = t&63;
  const int lr = lane&15, lg = lane>>4;
  const int sh4 = 4*lr;
  const int flat = blockIdx.x;
  const int vid = (flat & 7)*128 + (flat >> 3);   // XCD swizzle: 8 bh per XCD
  const int bh = vid >> 4, qt = vid & 15;
  const int b = bh >> 4, h = bh & 15;
  const int qb = qt*128 + wave*32;

  const f16* kbase = Kh + (size_t)b*S_*D_ + h*64;
  const f16* vbase = Vt + (size_t)bh*DK_*S_;

  f16x8 qf[2][2];
  #pragma unroll
  for (int qi=0; qi<2; qi++)
    #pragma unroll
    for (int s=0; s<2; s++)
      qf[qi][s] = *(const f16x8*)&Qh[(size_t)(b*S_ + qb + qi*16 + lr)*D_ + h*64 + s*32 + lg*8];

  float2 st[2][4];
  #pragma unroll
  for (int qi=0;qi<2;qi++)
    #pragma unroll
    for (int j=0;j<4;j++)
      st[qi][j] = stats[(size_t)bh*S_ + qb + qi*16 + lg*4 + j];

  f32x4 ct[4][2] = {};

  for (int kt=0; kt<32; kt++) {
    f32x4 sf[2][4] = {};
    #pragma unroll
    for (int s=0;s<2;s++)
      #pragma unroll
      for (int f=0;f<4;f++) {
        f16x8 kf = *(const f16x8*)&kbase[(size_t)(kt*64 + 4*lr + f)*D_ + s*32 + lg*8];
        #pragma unroll
        for (int qi=0;qi<2;qi++)
          sf[qi][f] = __builtin_amdgcn_mfma_f32_16x16x32_f16(qf[qi][s], kf, sf[qi][f],0,0,0);
      }
    uint2 kw = *(const uint2*)&kpw[b*64 + kt*2];
    #pragma unroll
    for (int qi=0;qi<2;qi++)
      #pragma unroll
      for (int j=0;j<4;j++) {
        int qrow = qb + qi*16 + lg*4 + j;
        uint2 aw = *(const uint2*)&amw[(size_t)qrow*64 + kt*2];
        uint32_t a0 = aw.x | kw.x, a1 = aw.y | kw.y;
        int nb = (int)((((uint64_t)a1<<32) | a0) >> sh4) & 15;
        float x0 = (nb&1) ? NEGINF : sf[qi][0][j];
        float x1 = (nb&2) ? NEGINF : sf[qi][1][j];
        float x2 = (nb&4) ? NEGINF : sf[qi][2][j];
        float x3 = (nb&8) ? NEGINF : sf[qi][3][j];
        float mgv = st[qi][j].x, ilv = st[qi][j].y;
        float e0 = EXP2F(x0 - mgv) * ilv;
        float e1 = EXP2F(x1 - mgv) * ilv;
        float e2 = EXP2F(x2 - mgv) * ilv;
        float e3 = EXP2F(x3 - mgv) * ilv;
        f32x4 ev = {e0, e1, e2, e3};
        __builtin_nontemporal_store(ev,
            (f32x4*)&attnp[((size_t)bh*S_ + qrow)*S_ + kt*64 + sh4]);
        f16x4 pv4; pv4[0]=(f16)e0; pv4[1]=(f16)e1; pv4[2]=(f16)e2; pv4[3]=(f16)e3;
        *(f16x4*)&Pl[wave][qi*16 + lg*4 + j][sh4] = pv4;
      }
    // PV: va direct from L2-resident Vt[bh][dk][s]; pb from per-wave Pl (lgkmcnt ordering)
    #pragma unroll
    for (int s=0;s<2;s++) {
      f16x8 pb0 = *(const f16x8*)&Pl[wave][lr][s*32 + lg*8];
      f16x8 pb1 = *(const f16x8*)&Pl[wave][16 + lr][s*32 + lg*8];
      #pragma unroll
      for (int mf=0; mf<4; mf++) {
        f16x8 va = *(const f16x8*)&vbase[(size_t)(mf*16 + lr)*S_ + kt*64 + s*32 + lg*8];
        ct[mf][0] = __builtin_amdgcn_mfma_f32_16x16x32_f16(va, pb0, ct[mf][0],0,0,0);
        ct[mf][1] = __builtin_amdgcn_mfma_f32_16x16x32_f16(va, pb1, ct[mf][1],0,0,0);
      }
    }
  }

  // ct[mf][qi]: row dk = mf*16+lg*4+j, col q = qi*16+lr (already normalized) -> [q][dk]
  #pragma unroll
  for (int mf=0; mf<4; mf++)
    #pragma unroll
    for (int qi=0; qi<2; qi++) {
      f16x4 o;
      #pragma unroll
      for (int j=0;j<4;j++) o[j] = (f16)ct[mf][qi][j];
      *(f16x4*)&Pl[wave][qi*16 + lr][mf*16 + lg*4] = o;
    }
  __builtin_amdgcn_s_waitcnt(0);  // drain own LDS writes (per-wave buffer)
  #pragma unroll
  for (int i=0;i<4;i++) {
    int idx = i*64 + lane;
    int row = idx >> 3, ch = idx & 7;
    f16x8 o = *(const f16x8*)&Pl[wave][row][ch*8];
    *(f16x8*)&ctx[(size_t)(b*S_ + qb + row)*D_ + h*64 + ch*8] = o;
  }
}

// ---------------- launch ----------------
extern "C" void kernel_launch(void* const* d_in, const int* in_sizes, int n_in,
                              void* d_out, int out_size, void* d_ws, size_t ws_size,
                              hipStream_t stream) {
  const float* src = (const float*)d_in[0];
  const int*   am  = (const int*)d_in[1];
  const int*   kp  = (const int*)d_in[2];
  const float* Wq  = (const float*)d_in[3];
  const float* bq  = (const float*)d_in[4];
  const float* Wk  = (const float*)d_in[5];
  const float* bk  = (const float*)d_in[6];
  const float* Wv  = (const float*)d_in[7];
  const float* bv  = (const float*)d_in[8];
  const float* Wo  = (const float*)d_in[9];
  const float* bo  = (const float*)d_in[10];

  const size_t need = (size_t)M_*D_*2        // Xh
                    + (size_t)4*D_*D_*2      // Wth
                    + (size_t)4*M_*D_*2      // Qh,Kh,Vt,CT
                    + (size_t)S_*S_/8        // amw
                    + (size_t)B_*S_/8        // kpw
                    + (size_t)M_*8;          // stats
  if (ws_size < need) return;

  char* w = (char*)d_ws;
  f16* Xh  = (f16*)w;  w += (size_t)M_*D_*2;
  f16* Wth = (f16*)w;  w += (size_t)4*D_*D_*2;
  f16* Qh  = (f16*)w;  w += (size_t)M_*D_*2;
  f16* Kh  = (f16*)w;  w += (size_t)M_*D_*2;
  f16* Vt  = (f16*)w;  w += (size_t)M_*D_*2;
  f16* CT  = (f16*)w;  w += (size_t)M_*D_*2;
  uint32_t* amw = (uint32_t*)w; w += (size_t)S_*S_/8;
  uint32_t* kpw = (uint32_t*)w; w += (size_t)B_*S_/8;
  float2* stats = (float2*)w;

  float* outp  = (float*)d_out;
  float* attnp = outp + (size_t)M_*D_;

  k_cvt_src<<<M_*D_/8/256, 256, 0, stream>>>(src, Xh);
  k_cvt_wt<<<dim3(16,16), 256, 0, stream>>>(Wq, Wth + 0*(size_t)D_*D_);
  k_cvt_wt<<<dim3(16,16), 256, 0, stream>>>(Wk, Wth + 1*(size_t)D_*D_);
  k_cvt_wt<<<dim3(16,16), 256, 0, stream>>>(Wv, Wth + 2*(size_t)D_*D_);
  k_cvt_wt<<<dim3(16,16), 256, 0, stream>>>(Wo, Wth + 3*(size_t)D_*D_);
  k_mask_words<<<S_*S_/64/4, 256, 0, stream>>>(am, amw);
  k_mask_words<<<B_*S_/64/4, 256, 0, stream>>>(kp, kpw);
  k_gemm<0><<<dim3(8,64), 256, 0, stream>>>(Xh, Wth + 0*(size_t)D_*D_, bq, Qh);
  k_gemm<1><<<dim3(8,64), 256, 0, stream>>>(Xh, Wth + 1*(size_t)D_*D_, bk, Kh);
  k_gemm<2><<<dim3(8,64), 256, 0, stream>>>(Xh, Wth + 2*(size_t)D_*D_, bv, Vt);
  k_stats<<<1024, 256, 0, stream>>>(Qh, Kh, amw, kpw, stats);
  k_attn2<<<1024, 256, 0, stream>>>(Qh, Kh, Vt, amw, kpw, stats, attnp, CT);
  k_gemm<3><<<dim3(8,64), 256, 0, stream>>>(CT, Wth + 3*(size_t)D_*D_, bo, outp);
}

// Round 8
// 459.342 us; speedup vs baseline: 1.4606x; 1.4606x over previous
//
#include <hip/hip_runtime.h>
#include <stdint.h>
#include <stddef.h>

#define B_ 4
#define S_ 2048
#define D_ 1024
#define H_ 16
#define DK_ 64
#define M_ (B_*S_)
#define NEGINF (-1e30f)
#define THR_ 8.0f

#if __has_builtin(__builtin_amdgcn_exp2f)
#define EXP2F(x) __builtin_amdgcn_exp2f(x)
#else
#define EXP2F(x) exp2f(x)
#endif

typedef _Float16 f16;
typedef __attribute__((ext_vector_type(8))) _Float16 f16x8;
typedef __attribute__((ext_vector_type(4))) _Float16 f16x4;
typedef __attribute__((ext_vector_type(4))) float f32x4;

// async global->LDS, 16B per lane; LDS dest = wave-uniform base + lane*16
__device__ __forceinline__ void gload16(const void* g, void* l) {
  __builtin_amdgcn_global_load_lds(
      (const __attribute__((address_space(1))) uint32_t*)g,
      (__attribute__((address_space(3))) uint32_t*)l, 16, 0, 0);
}

// ---------------- convert src f32 -> f16 ----------------
__global__ void k_cvt_src(const float* __restrict__ in, f16* __restrict__ out) {
  int i = blockIdx.x*256 + threadIdx.x;
  const f32x4* p = (const f32x4*)in;
  f32x4 a = p[2*i], b = p[2*i+1];
  f16x8 o;
  o[0]=(f16)a[0]; o[1]=(f16)a[1]; o[2]=(f16)a[2]; o[3]=(f16)a[3];
  o[4]=(f16)b[0]; o[5]=(f16)b[1]; o[6]=(f16)b[2]; o[7]=(f16)b[3];
  ((f16x8*)out)[i] = o;
}

// ---------------- convert + transpose all 4 weights: W[k][n] -> Wt[n][k] f16 ----------------
__global__ void k_cvt_wt(const float* __restrict__ W0, const float* __restrict__ W1,
                         const float* __restrict__ W2, const float* __restrict__ W3,
                         f16* __restrict__ WtBase) {
  __shared__ float tile[64][65];
  const float* W = (blockIdx.z==0) ? W0 : (blockIdx.z==1) ? W1 : (blockIdx.z==2) ? W2 : W3;
  f16* Wt = WtBase + (size_t)blockIdx.z*D_*D_;
  int k0 = blockIdx.x*64, n0 = blockIdx.y*64;
  int t = threadIdx.x;
  int c4 = t & 15, r0 = t >> 4;
  #pragma unroll
  for (int i = 0; i < 4; i++) {
    int r = r0 + i*16;
    f32x4 v = *(const f32x4*)&W[(size_t)(k0 + r)*D_ + n0 + c4*4];
    tile[r][c4*4+0]=v[0]; tile[r][c4*4+1]=v[1]; tile[r][c4*4+2]=v[2]; tile[r][c4*4+3]=v[3];
  }
  __syncthreads();
  #pragma unroll
  for (int i = 0; i < 4; i++) {
    int nr = r0 + i*16;
    int kc = c4*4;
    f16x4 o;
    o[0]=(f16)tile[kc+0][nr]; o[1]=(f16)tile[kc+1][nr];
    o[2]=(f16)tile[kc+2][nr]; o[3]=(f16)tile[kc+3][nr];
    *(f16x4*)&Wt[(size_t)(n0+nr)*D_ + k0 + kc] = o;
  }
}

// ---------------- both bool(int32) masks -> bitmask words (one launch) ----------------
__global__ void k_masks(const int* __restrict__ am, const int* __restrict__ kp,
                        uint32_t* __restrict__ amw, uint32_t* __restrict__ kpw) {
  int g = blockIdx.x*4 + (threadIdx.x>>6);
  int lane = threadIdx.x & 63;
  const int NAM = S_*S_/64;
  int v; uint32_t* dst;
  if (g < NAM) { v = am[(size_t)g*64 + lane]; dst = amw + (size_t)g*2; }
  else         { int g2 = g - NAM; v = kp[(size_t)g2*64 + lane]; dst = kpw + (size_t)g2*2; }
  unsigned long long bal = __ballot(v != 0);
  if (lane == 0) { dst[0] = (uint32_t)bal; dst[1] = (uint32_t)(bal>>32); }
}

// ---------------- GEMM (m97 structure): C[m][n] = A[m][:]*Wt[n][:] + bias ----------------
// MODE 0: Q out f16, scaled by 0.125*log2(e).  MODE 1: K out f16.
// MODE 2: V out f16 transposed -> Vt[bh][dk][s].  MODE 3: f32 out.
template<int MODE>
__global__ __launch_bounds__(256, 2) void k_gemm(
    const f16* __restrict__ A, const f16* __restrict__ Wt,
    const float* __restrict__ bias, void* __restrict__ outp) {
  __shared__ f16 As[128][64];   // linear: required by global_load_lds
  __shared__ f16 Bs[128][64];
  const int t = threadIdx.x;
  const int wave = t>>6, lane = t&63;
  const int lr = lane&15, lg = lane>>4;
  const int wr = wave>>1, wc = wave&1;
  const int m0 = blockIdx.y*128, n0 = blockIdx.x*128;
  const int srow = lane>>3, scol = (lane&7)*8;

  const f16* ga = A  + (size_t)m0*D_;
  const f16* gb = Wt + (size_t)n0*D_;

  f32x4 acc[4][4] = {};
  for (int kk=0; kk<16; kk++) {
    __syncthreads();
    #pragma unroll
    for (int i=0;i<4;i++){
      int rbase = i*32 + wave*8;
      gload16(&ga[(size_t)(rbase+srow)*D_ + kk*64 + scol], &As[rbase][0]);
      gload16(&gb[(size_t)(rbase+srow)*D_ + kk*64 + scol], &Bs[rbase][0]);
    }
    __syncthreads();   // drains vmcnt(0): tiles ready
    #pragma unroll
    for (int s=0;s<2;s++) {
      f16x8 af[4], bf[4];
      #pragma unroll
      for (int i=0;i<4;i++) af[i] = *(const f16x8*)&As[wr*64 + i*16 + lr][s*32 + lg*8];
      #pragma unroll
      for (int i=0;i<4;i++) bf[i] = *(const f16x8*)&Bs[wc*64 + i*16 + lr][s*32 + lg*8];
      #pragma unroll
      for (int i=0;i<4;i++)
        #pragma unroll
        for (int j=0;j<4;j++)
          acc[i][j] = __builtin_amdgcn_mfma_f32_16x16x32_f16(af[i], bf[j], acc[i][j],0,0,0);
    }
  }
  #pragma unroll
  for (int fn=0; fn<4; fn++) {
    int n = n0 + wc*64 + fn*16 + lr;
    float bv = bias[n];
    #pragma unroll
    for (int fm=0; fm<4; fm++) {
      int mrow = m0 + wr*64 + fm*16 + lg*4;
      if constexpr (MODE == 0) {
        f16* O = (f16*)outp;
        #pragma unroll
        for (int j=0;j<4;j++) O[(size_t)(mrow+j)*D_ + n] = (f16)((acc[fm][fn][j] + bv)*0.1803368801111204f);
      } else if constexpr (MODE == 1) {
        f16* O = (f16*)outp;
        #pragma unroll
        for (int j=0;j<4;j++) O[(size_t)(mrow+j)*D_ + n] = (f16)(acc[fm][fn][j] + bv);
      } else if constexpr (MODE == 2) {
        f16* O = (f16*)outp;
        int hh = n >> 6, dk = n & 63;
        int bb = mrow >> 11, ss = mrow & (S_-1);
        f16x4 o;
        #pragma unroll
        for (int j=0;j<4;j++) o[j] = (f16)(acc[fm][fn][j] + bv);
        *(f16x4*)&O[((size_t)(bb*H_ + hh)*DK_ + dk)*S_ + ss] = o;
      } else {
        float* O = (float*)outp;
        #pragma unroll
        for (int j=0;j<4;j++) O[(size_t)(mrow+j)*D_ + n] = acc[fm][fn][j] + bv;
      }
    }
  }
}

// ---------------- single-pass flash: context + per-row stats (NO attn store) ----------------
// K LDS key-permuted (virtual row (r&3)*16+(r>>2)): lane's 4 scores = keys 4*lr+f.
// Online softmax with defer-max (THR=8, exp2 domain): wave-uniform running max per row,
// cross-lane reduce + accumulator rescale only when a tile max exceeds m+THR.
__global__ __launch_bounds__(256, 2) void k_flash(
    const f16* __restrict__ Qh, const f16* __restrict__ Kh, const f16* __restrict__ Vt,
    const uint32_t* __restrict__ amw, const uint32_t* __restrict__ kpw,
    float2* __restrict__ stats, f16* __restrict__ ctx) {
  __shared__ f16 Kt[64][72];
  __shared__ f16 Vtt[64][72];
  __shared__ f16 Pl[4][32][72];
  __shared__ float ssc[4][2][16];

  const int t = threadIdx.x, wave = t>>6, lane = t&63;
  const int lr = lane&15, lg = lane>>4;
  const int sh4 = 4*lr;
  const int flat = blockIdx.x;
  const int vid = (flat & 7)*128 + (flat >> 3);   // XCD swizzle: 8 bh per XCD
  const int bh = vid >> 4, qt = vid & 15;
  const int b = bh >> 4, h = bh & 15;
  const int qb = qt*128 + wave*32;

  const f16* kbase = Kh + (size_t)b*S_*D_ + h*64;
  const f16* vbase = Vt + (size_t)bh*DK_*S_;

  f16x8 qf[2][2];
  #pragma unroll
  for (int qi=0; qi<2; qi++)
    #pragma unroll
    for (int s=0; s<2; s++)
      qf[qi][s] = *(const f16x8*)&Qh[(size_t)(b*S_ + qb + qi*16 + lr)*D_ + h*64 + s*32 + lg*8];

  const int rA = t>>3, cA = t&7;
  const int rB = 32 + (t>>3);
  const int vA = ((rA&3)<<4) | (rA>>2);
  const int vB = ((rB&3)<<4) | (rB>>2);

  float mu[2][4], mg[2][4], l_[2][4];
  #pragma unroll
  for (int qi=0;qi<2;qi++)
    #pragma unroll
    for (int j=0;j<4;j++){ mu[qi][j]=NEGINF; mg[qi][j]=0.f; l_[qi][j]=0.f; }
  f32x4 ct[4][2] = {};

  f16x8 sk0 = *(const f16x8*)&kbase[(size_t)rA*D_ + cA*8];
  f16x8 sk1 = *(const f16x8*)&kbase[(size_t)rB*D_ + cA*8];
  f16x8 sv0 = *(const f16x8*)&vbase[(size_t)rA*S_ + cA*8];
  f16x8 sv1 = *(const f16x8*)&vbase[(size_t)rB*S_ + cA*8];

  for (int kt=0; kt<32; kt++) {
    __syncthreads();
    *(f16x8*)&Kt[vA][cA*8]  = sk0;  *(f16x8*)&Kt[vB][cA*8]  = sk1;
    *(f16x8*)&Vtt[rA][cA*8] = sv0;  *(f16x8*)&Vtt[rB][cA*8] = sv1;
    __syncthreads();
    if (kt < 31) {
      sk0 = *(const f16x8*)&kbase[(size_t)((kt+1)*64 + rA)*D_ + cA*8];
      sk1 = *(const f16x8*)&kbase[(size_t)((kt+1)*64 + rB)*D_ + cA*8];
      sv0 = *(const f16x8*)&vbase[(size_t)rA*S_ + (kt+1)*64 + cA*8];
      sv1 = *(const f16x8*)&vbase[(size_t)rB*S_ + (kt+1)*64 + cA*8];
    }
    f32x4 sf[2][4] = {};
    #pragma unroll
    for (int s=0;s<2;s++)
      #pragma unroll
      for (int f=0;f<4;f++) {
        f16x8 kf = *(const f16x8*)&Kt[f*16 + lr][s*32 + lg*8];
        #pragma unroll
        for (int qi=0;qi<2;qi++)
          sf[qi][f] = __builtin_amdgcn_mfma_f32_16x16x32_f16(qf[qi][s], kf, sf[qi][f],0,0,0);
      }
    uint32_t kw0 = kpw[b*64 + kt*2], kw1 = kpw[b*64 + kt*2 + 1];
    int nib[2][4]; float tmx[2][4]; int need = 0;
    #pragma unroll
    for (int qi=0;qi<2;qi++)
      #pragma unroll
      for (int j=0;j<4;j++) {
        int qrow = qb + qi*16 + lg*4 + j;
        uint32_t a0 = amw[(size_t)qrow*64 + kt*2]     | kw0;
        uint32_t a1 = amw[(size_t)qrow*64 + kt*2 + 1] | kw1;
        int nb = (int)((((uint64_t)a1<<32) | a0) >> sh4) & 15;
        nib[qi][j] = nb;
        float x0 = (nb&1) ? NEGINF : sf[qi][0][j];
        float x1 = (nb&2) ? NEGINF : sf[qi][1][j];
        float x2 = (nb&4) ? NEGINF : sf[qi][2][j];
        float x3 = (nb&8) ? NEGINF : sf[qi][3][j];
        float tm = fmaxf(fmaxf(x0,x1), fmaxf(x2,x3));
        tmx[qi][j] = tm;
        need |= (tm > mu[qi][j] + THR_) ? 1 : 0;
      }
    if (__any(need)) {   // rare wave-uniform rescale
      #pragma unroll
      for (int qi=0;qi<2;qi++)
        #pragma unroll
        for (int j=0;j<4;j++) {
          float gm = tmx[qi][j];
          #pragma unroll
          for (int d=1; d<16; d<<=1) gm = fmaxf(gm, __shfl_xor(gm, d));
          float mnew = fmaxf(mu[qi][j], gm);
          float mgn = (mnew <= NEGINF) ? 0.f : mnew;
          float sc = EXP2F(mg[qi][j] - mgn);
          l_[qi][j] *= sc;
          mu[qi][j] = mnew; mg[qi][j] = mgn;
          if (lr == 0) ssc[wave][qi][lg*4+j] = sc;
        }
      asm volatile("s_waitcnt lgkmcnt(0)" ::: "memory");
      __builtin_amdgcn_sched_barrier(0);
      float sv_0 = ssc[wave][0][lr], sv_1 = ssc[wave][1][lr];
      #pragma unroll
      for (int mf=0; mf<4; mf++)
        #pragma unroll
        for (int c=0;c<4;c++) { ct[mf][0][c] *= sv_0; ct[mf][1][c] *= sv_1; }
    }
    #pragma unroll
    for (int qi=0;qi<2;qi++)
      #pragma unroll
      for (int j=0;j<4;j++) {
        int nb = nib[qi][j];
        float x0 = (nb&1) ? NEGINF : sf[qi][0][j];
        float x1 = (nb&2) ? NEGINF : sf[qi][1][j];
        float x2 = (nb&4) ? NEGINF : sf[qi][2][j];
        float x3 = (nb&8) ? NEGINF : sf[qi][3][j];
        float e0 = EXP2F(x0 - mg[qi][j]);
        float e1 = EXP2F(x1 - mg[qi][j]);
        float e2 = EXP2F(x2 - mg[qi][j]);
        float e3 = EXP2F(x3 - mg[qi][j]);
        l_[qi][j] += (e0+e1)+(e2+e3);
        f16x4 pv4; pv4[0]=(f16)e0; pv4[1]=(f16)e1; pv4[2]=(f16)e2; pv4[3]=(f16)e3;
        *(f16x4*)&Pl[wave][qi*16 + lg*4 + j][sh4] = pv4;
      }
    #pragma unroll
    for (int s=0;s<2;s++) {
      f16x8 pb0 = *(const f16x8*)&Pl[wave][lr][s*32 + lg*8];
      f16x8 pb1 = *(const f16x8*)&Pl[wave][16 + lr][s*32 + lg*8];
      #pragma unroll
      for (int mf=0; mf<4; mf++) {
        f16x8 va = *(const f16x8*)&Vtt[mf*16 + lr][s*32 + lg*8];
        ct[mf][0] = __builtin_amdgcn_mfma_f32_16x16x32_f16(va, pb0, ct[mf][0],0,0,0);
        ct[mf][1] = __builtin_amdgcn_mfma_f32_16x16x32_f16(va, pb1, ct[mf][1],0,0,0);
      }
    }
  }

  // merge per-lane l across the 16-lane group; publish stats; normalize context
  #pragma unroll
  for (int qi=0;qi<2;qi++)
    #pragma unroll
    for (int j=0;j<4;j++) {
      float ls = l_[qi][j];
      #pragma unroll
      for (int d=1; d<16; d<<=1) ls += __shfl_xor(ls, d);
      float ilv = (ls > 0.f) ? 1.f/ls : 0.f;
      if (lr == 0) {
        ssc[wave][qi][lg*4+j] = ilv;
        stats[(size_t)bh*S_ + qb + qi*16 + lg*4 + j] = make_float2(mg[qi][j], ilv);
      }
    }
  asm volatile("s_waitcnt lgkmcnt(0)" ::: "memory");
  __builtin_amdgcn_sched_barrier(0);
  float il0 = ssc[wave][0][lr], il1 = ssc[wave][1][lr];

  // ct[mf][qi]: row dk = mf*16+lg*4+j, col q = qi*16+lr  ->  bounce to [q][dk]
  #pragma unroll
  for (int mf=0; mf<4; mf++)
    #pragma unroll
    for (int qi=0; qi<2; qi++) {
      float ilc = qi ? il1 : il0;
      f16x4 o;
      #pragma unroll
      for (int j=0;j<4;j++) o[j] = (f16)(ct[mf][qi][j] * ilc);
      *(f16x4*)&Pl[wave][qi*16 + lr][mf*16 + lg*4] = o;
    }
  __builtin_amdgcn_s_waitcnt(0);
  #pragma unroll
  for (int i=0;i<4;i++) {
    int idx = i*64 + lane;
    int row = idx >> 3, ch = idx & 7;
    f16x8 o = *(const f16x8*)&Pl[wave][row][ch*8];
    *(f16x8*)&ctx[(size_t)(b*S_ + qb + row)*D_ + h*64 + ch*8] = o;
  }
}

// ---------------- attn writer: one-shot 128x128 score tile, nontemporal streaming stores ----------------
__global__ __launch_bounds__(256, 2) void k_attnw(
    const f16* __restrict__ Qh, const f16* __restrict__ Kh,
    const uint32_t* __restrict__ amw, const uint32_t* __restrict__ kpw,
    const float2* __restrict__ stats, float* __restrict__ attnp) {
  __shared__ f16 Ks[128][72];   // key-permuted within each 64-half
  const int t = threadIdx.x, wave = t>>6, lane = t&63;
  const int lr = lane&15, lg = lane>>4;
  const int sh4 = 4*lr;
  const int ktb = blockIdx.x, qt = blockIdx.y, bh = blockIdx.z;
  const int b = bh >> 4, h = bh & 15;
  const int qb = qt*128, kb = ktb*128;

  #pragma unroll
  for (int i=0;i<4;i++) {
    int q = i*256 + t;
    int r = q>>3, c = q&7;
    int half = r>>6, rr = r&63;
    int v = ((rr&3)<<4) | (rr>>2);
    *(f16x8*)&Ks[half*64 + v][c*8] =
        *(const f16x8*)&Kh[(size_t)(b*S_ + kb + r)*D_ + h*64 + c*8];
  }
  f16x8 qf[2][2];
  #pragma unroll
  for (int qi=0; qi<2; qi++)
    #pragma unroll
    for (int s=0; s<2; s++)
      qf[qi][s] = *(const f16x8*)&Qh[(size_t)(b*S_ + qb + wave*32 + qi*16 + lr)*D_ + h*64 + s*32 + lg*8];
  __syncthreads();   // only barrier in the kernel

  f32x4 sf[2][8] = {};
  #pragma unroll
  for (int s=0;s<2;s++)
    #pragma unroll
    for (int f=0;f<8;f++) {
      f16x8 kf = *(const f16x8*)&Ks[f*16 + lr][s*32 + lg*8];
      #pragma unroll
      for (int qi=0;qi<2;qi++)
        sf[qi][f] = __builtin_amdgcn_mfma_f32_16x16x32_f16(qf[qi][s], kf, sf[qi][f],0,0,0);
    }

  uint32_t kw[4];
  #pragma unroll
  for (int i=0;i<4;i++) kw[i] = kpw[b*64 + ktb*4 + i];

  #pragma unroll
  for (int qi=0;qi<2;qi++)
    #pragma unroll
    for (int j=0;j<4;j++) {
      int qrow = qb + wave*32 + qi*16 + lg*4 + j;
      float2 st = stats[(size_t)bh*S_ + qrow];
      #pragma unroll
      for (int half=0; half<2; half++) {
        uint32_t a0 = amw[(size_t)qrow*64 + ktb*4 + half*2]     | kw[half*2];
        uint32_t a1 = amw[(size_t)qrow*64 + ktb*4 + half*2 + 1] | kw[half*2+1];
        int nb = (int)((((uint64_t)a1<<32) | a0) >> sh4) & 15;
        float x0 = (nb&1) ? NEGINF : sf[qi][half*4+0][j];
        float x1 = (nb&2) ? NEGINF : sf[qi][half*4+1][j];
        float x2 = (nb&4) ? NEGINF : sf[qi][half*4+2][j];
        float x3 = (nb&8) ? NEGINF : sf[qi][half*4+3][j];
        f32x4 ev;
        ev[0] = EXP2F(x0 - st.x) * st.y;
        ev[1] = EXP2F(x1 - st.x) * st.y;
        ev[2] = EXP2F(x2 - st.x) * st.y;
        ev[3] = EXP2F(x3 - st.x) * st.y;
        __builtin_nontemporal_store(ev,
            (f32x4*)&attnp[((size_t)bh*S_ + qrow)*S_ + kb + half*64 + sh4]);
      }
    }
}

// ---------------- launch ----------------
extern "C" void kernel_launch(void* const* d_in, const int* in_sizes, int n_in,
                              void* d_out, int out_size, void* d_ws, size_t ws_size,
                              hipStream_t stream) {
  const float* src = (const float*)d_in[0];
  const int*   am  = (const int*)d_in[1];
  const int*   kp  = (const int*)d_in[2];
  const float* Wq  = (const float*)d_in[3];
  const float* bq  = (const float*)d_in[4];
  const float* Wk  = (const float*)d_in[5];
  const float* bk  = (const float*)d_in[6];
  const float* Wv  = (const float*)d_in[7];
  const float* bv  = (const float*)d_in[8];
  const float* Wo  = (const float*)d_in[9];
  const float* bo  = (const float*)d_in[10];

  const size_t need = (size_t)M_*D_*2        // Xh
                    + (size_t)4*D_*D_*2      // Wth
                    + (size_t)4*M_*D_*2      // Qh,Kh,Vt,CT
                    + (size_t)S_*S_/8        // amw
                    + (size_t)B_*S_/8        // kpw
                    + (size_t)M_*8;          // stats
  if (ws_size < need) return;

  char* w = (char*)d_ws;
  f16* Xh  = (f16*)w;  w += (size_t)M_*D_*2;
  f16* Wth = (f16*)w;  w += (size_t)4*D_*D_*2;
  f16* Qh  = (f16*)w;  w += (size_t)M_*D_*2;
  f16* Kh  = (f16*)w;  w += (size_t)M_*D_*2;
  f16* Vt  = (f16*)w;  w += (size_t)M_*D_*2;
  f16* CT  = (f16*)w;  w += (size_t)M_*D_*2;
  uint32_t* amw = (uint32_t*)w; w += (size_t)S_*S_/8;
  uint32_t* kpw = (uint32_t*)w; w += (size_t)B_*S_/8;
  float2* stats = (float2*)w;

  float* outp  = (float*)d_out;
  float* attnp = outp + (size_t)M_*D_;

  k_cvt_src<<<M_*D_/8/256, 256, 0, stream>>>(src, Xh);
  k_cvt_wt<<<dim3(16,16,4), 256, 0, stream>>>(Wq, Wk, Wv, Wo, Wth);
  k_masks<<<(S_*S_/64 + B_*S_/64)/4, 256, 0, stream>>>(am, kp, amw, kpw);
  k_gemm<0><<<dim3(8,64), 256, 0, stream>>>(Xh, Wth + 0*(size_t)D_*D_, bq, Qh);
  k_gemm<1><<<dim3(8,64), 256, 0, stream>>>(Xh, Wth + 1*(size_t)D_*D_, bk, Kh);
  k_gemm<2><<<dim3(8,64), 256, 0, stream>>>(Xh, Wth + 2*(size_t)D_*D_, bv, Vt);
  k_flash<<<1024, 256, 0, stream>>>(Qh, Kh, Vt, amw, kpw, stats, CT);
  k_gemm<3><<<dim3(8,64), 256, 0, stream>>>(CT, Wth + 3*(size_t)D_*D_, bo, outp);
  k_attnw<<<dim3(16,16,64), 256, 0, stream>>>(Qh, Kh, amw, kpw, stats, attnp);
}